// Round 2
// baseline (1075.581 us; speedup 1.0000x reference)
//
#include <hip/hip_runtime.h>
#include <stdint.h>

// MeshConvPoint: B=8, C=64, V=25000, D=12, O=64
// out[b,o,v] = bias[o] + sum_c W0[o,c]*x[b,c,v] + (1/deg) * sum_{d<deg} y1[b,o,nbr[b,v,d]]
// Phase 1 (ykern_gemm): y0[b][v][o] = bias + W0@x, y1[b][v][o] = W1@x, both bf16 v-major
//   rows (128 B) so phase 2's neighbor gather reads whole cache lines.
// Phase 2 (gather_out): out = y0row + invdeg * sum(y1 rows of neighbors).
// XCD pinning: blockIdx.x % 8 == batch, so each XCD's 4 MB L2 holds one batch's
// y1 (3.2 MB bf16) across both phases. Streaming data uses nontemporal ld/st.

#define NB 8
#define NC 64
#define NV 25000
#define ND 12
#define NO 64
#define VT 98  // ceil(25000/256) vertex tiles

typedef uint32_t u32x4 __attribute__((ext_vector_type(4)));

__device__ inline uint32_t bf16pack(float a, float b) {
    uint32_t ua = __float_as_uint(a), ub = __float_as_uint(b);
    ua = (ua + 0x7fffu + ((ua >> 16) & 1u)) >> 16;
    ub = (ub + 0x7fffu + ((ub >> 16) & 1u)) >> 16;
    return ua | (ub << 16);
}
__device__ inline float blo(uint32_t u) { return __uint_as_float(u << 16); }
__device__ inline float bhi(uint32_t u) { return __uint_as_float(u & 0xffff0000u); }

// ---- K0: W[o][c][k] -> Wt[k][c][o] ----
__global__ __launch_bounds__(256) void wt_kernel(const float* __restrict__ W,
                                                 float* __restrict__ Wt) {
    int i = blockIdx.x * 256 + threadIdx.x;  // [k][c][o]
    int k = i >> 12, c = (i >> 6) & 63, o = i & 63;
    Wt[i] = W[o * (NC * 2) + c * 2 + k];
}

// ---- K1: both planes, bf16 v-major output ----
__global__ __launch_bounds__(256) void ykern_gemm(const float* __restrict__ x,
                                                  const float* __restrict__ Wt,
                                                  const float* __restrict__ bias,
                                                  uint32_t* __restrict__ y0,
                                                  uint32_t* __restrict__ y1) {
    const int b = blockIdx.x & 7;        // XCD pin: block->XCD is ~%8
    const int tile = blockIdx.x >> 3;
    const int v = tile * 256 + threadIdx.x;
    const int vc = v < NV ? v : NV - 1;
    const bool valid = (v < NV);

    const float* xb = x + (size_t)b * NC * NV;
    float xr[NC];
#pragma unroll
    for (int c = 0; c < NC; ++c)
        xr[c] = __builtin_nontemporal_load(xb + (size_t)c * NV + vc);

    const float* W0 = Wt;            // [c][o]
    const float* W1 = Wt + NC * NO;  // [c][o]
    uint32_t* y0row = y0 + ((size_t)b * NV + vc) * 32;  // 64 bf16 = 32 dwords
    uint32_t* y1row = y1 + ((size_t)b * NV + vc) * 32;

#pragma unroll 1
    for (int oc = 0; oc < NO; oc += 16) {
        float a0[16], a1[16];
#pragma unroll
        for (int j = 0; j < 16; ++j) { a0[j] = bias[oc + j]; a1[j] = 0.0f; }
#pragma unroll
        for (int c = 0; c < NC; ++c) {
            const float xc = xr[c];
#pragma unroll
            for (int j = 0; j < 16; ++j) {
                a0[j] = __builtin_fmaf(W0[c * NO + oc + j], xc, a0[j]);
                a1[j] = __builtin_fmaf(W1[c * NO + oc + j], xc, a1[j]);
            }
        }
        if (valid) {
#pragma unroll
            for (int j = 0; j < 16; j += 8) {
                u32x4 p0 = {bf16pack(a0[j], a0[j + 1]), bf16pack(a0[j + 2], a0[j + 3]),
                            bf16pack(a0[j + 4], a0[j + 5]), bf16pack(a0[j + 6], a0[j + 7])};
                u32x4 p1 = {bf16pack(a1[j], a1[j + 1]), bf16pack(a1[j + 2], a1[j + 3]),
                            bf16pack(a1[j + 4], a1[j + 5]), bf16pack(a1[j + 6], a1[j + 7])};
                // y0 is read exactly once later: nontemporal. y1 is the hot gather
                // target: normal (cached) store so it stays in this XCD's L2.
                __builtin_nontemporal_store(p0, (u32x4*)(y0row + oc / 2 + j / 2));
                *(u32x4*)(y1row + oc / 2 + j / 2) = p1;
            }
        }
    }
}

// ---- K2: pure gather + combine + store ----
__global__ __launch_bounds__(256) void gather_out(const int* __restrict__ nbr,
                                                  const int* __restrict__ deg,
                                                  const uint32_t* __restrict__ y0,
                                                  const uint32_t* __restrict__ y1,
                                                  float* __restrict__ out) {
    const int b = blockIdx.x & 7;  // same XCD pin as producer
    const int tile = blockIdx.x >> 3;
    const int v = tile * 256 + threadIdx.x;
    const int vc = v < NV ? v : NV - 1;
    const bool valid = (v < NV);
    const size_t bv = (size_t)b * NV + vc;

    int idxr[ND];
    {
        const int4* p = reinterpret_cast<const int4*>(nbr + bv * ND);
        int4 a0 = p[0], a1 = p[1], a2 = p[2];
        idxr[0] = a0.x; idxr[1] = a0.y; idxr[2]  = a0.z; idxr[3]  = a0.w;
        idxr[4] = a1.x; idxr[5] = a1.y; idxr[6]  = a1.z; idxr[7]  = a1.w;
        idxr[8] = a2.x; idxr[9] = a2.y; idxr[10] = a2.z; idxr[11] = a2.w;
    }
    const int dg = deg[bv];
    const float inv = 1.0f / (float)dg;
    const uint32_t* y1b = y1 + (size_t)b * NV * 32;

    float ns[NO];
#pragma unroll
    for (int j = 0; j < NO; ++j) ns[j] = 0.0f;

#pragma unroll
    for (int d = 0; d < ND; ++d) {
        if (d < dg) {
            const u32x4* row = reinterpret_cast<const u32x4*>(y1b + (size_t)idxr[d] * 32);
#pragma unroll
            for (int q = 0; q < 8; ++q) {
                u32x4 u = row[q];
                ns[q * 8 + 0] += blo(u[0]); ns[q * 8 + 1] += bhi(u[0]);
                ns[q * 8 + 2] += blo(u[1]); ns[q * 8 + 3] += bhi(u[1]);
                ns[q * 8 + 4] += blo(u[2]); ns[q * 8 + 5] += bhi(u[2]);
                ns[q * 8 + 6] += blo(u[3]); ns[q * 8 + 7] += bhi(u[3]);
            }
        }
    }

    if (valid) {
        const u32x4* srow = reinterpret_cast<const u32x4*>(y0 + bv * 32);
#pragma unroll
        for (int q = 0; q < 8; ++q) {
            u32x4 u = __builtin_nontemporal_load(srow + q);
            float r[8];
            r[0] = blo(u[0]); r[1] = bhi(u[0]); r[2] = blo(u[1]); r[3] = bhi(u[1]);
            r[4] = blo(u[2]); r[5] = bhi(u[2]); r[6] = blo(u[3]); r[7] = bhi(u[3]);
#pragma unroll
            for (int t = 0; t < 8; ++t) {
                float val = __builtin_fmaf(inv, ns[q * 8 + t], r[t]);
                __builtin_nontemporal_store(val, out + ((size_t)b * NO + q * 8 + t) * NV + v);
            }
        }
    }
}

// ---- Fallback (workspace too small): correct but slow ----
__global__ __launch_bounds__(64) void fallback_kernel(const float* __restrict__ x,
                                                      const int* __restrict__ nbr,
                                                      const int* __restrict__ deg,
                                                      const float* __restrict__ W,
                                                      const float* __restrict__ bias,
                                                      float* __restrict__ out) {
    const int bvi = blockIdx.x;
    const int b = bvi / NV, v = bvi % NV;
    const int o = threadIdx.x;
    const int degv = deg[bvi];
    const float inv = 1.0f / (float)degv;
    float acc = bias[o];
    for (int c = 0; c < NC; ++c) {
        const float* xc = x + ((size_t)b * NC + c) * NV;
        float m = 0.0f;
        for (int d = 0; d < degv; ++d) m += xc[nbr[(size_t)bvi * ND + d]];
        acc += W[o * (NC * 2) + c * 2] * xc[v] + W[o * (NC * 2) + c * 2 + 1] * (m * inv);
    }
    out[((size_t)b * NO + o) * NV + v] = acc;
}

extern "C" void kernel_launch(void* const* d_in, const int* in_sizes, int n_in,
                              void* d_out, int out_size, void* d_ws, size_t ws_size,
                              hipStream_t stream) {
    const float* x    = (const float*)d_in[0];
    const int*   nbr  = (const int*)d_in[1];
    const int*   deg  = (const int*)d_in[2];
    const float* W    = (const float*)d_in[3];
    const float* bias = (const float*)d_in[4];
    float* out = (float*)d_out;

    const size_t wt_elems = (size_t)2 * NC * NO;                 // fp32
    const size_t yplane   = (size_t)NB * NV * 32;                // dwords per plane
    const size_t need = wt_elems * 4 + 2 * yplane * 4;
    if (ws_size >= need) {
        float* Wt = (float*)d_ws;
        uint32_t* y0 = (uint32_t*)(Wt + wt_elems);
        uint32_t* y1 = y0 + yplane;
        wt_kernel<<<dim3((2 * NC * NO) / 256), 256, 0, stream>>>(W, Wt);
        ykern_gemm<<<dim3(NB * VT), 256, 0, stream>>>(x, Wt, bias, y0, y1);
        gather_out<<<dim3(NB * VT), 256, 0, stream>>>(nbr, deg, y0, y1, out);
    } else {
        fallback_kernel<<<dim3(NB * NV), 64, 0, stream>>>(x, nbr, deg, W, bias, out);
    }
}

// Round 4
// 202.554 us; speedup vs baseline: 5.3101x; 5.3101x over previous
//
#include <hip/hip_runtime.h>
#include <stdint.h>

// MeshConvPoint: B=8, C=64, V=25000, D=12, O=64
// out[b,o,v] = bias[o] + sum_c W0[o,c]*x[b,c,v] + (1/deg)*sum_{d<deg} y1[b,o,nbr[b,v,d]]
//
// R4 = R3 with the compile fix (ext_vector u32x2 for nontemporal 8B store).
// MFMA GEMM: Y[128][v] = Wc[128][64] @ x[64][v], Wc = [W0;W1] stacked, bf16
// 16x16x32 MFMA, v-major bf16 output rows (128 B) so the gather kernel reads
// whole cache lines. Gather kernel does two 32-o halves to keep VGPRs low
// (R2 lesson: 96-VGPR + 64-deep x buffer spills -> 938 us).
// XCD pin: blockIdx.x & 7 == batch in both producer and consumer so each XCD's
// 4 MB L2 holds one batch's y1 (3.2 MB bf16).

#define NB 8
#define NC 64
#define NV 25000
#define ND 12
#define NO 64
#define VT 98          // ceil(25000/256) vertex tiles for gather
#define GT 391         // ceil(25000/64)  vertex tiles for gemm (64 v / block)

typedef uint32_t u32x4 __attribute__((ext_vector_type(4)));
typedef uint32_t u32x2 __attribute__((ext_vector_type(2)));
typedef __bf16  bf16x8 __attribute__((ext_vector_type(8)));
typedef float   f32x4  __attribute__((ext_vector_type(4)));

__device__ inline uint32_t bf16pack(float a, float b) {
    uint32_t ua = __float_as_uint(a), ub = __float_as_uint(b);
    ua = (ua + 0x7fffu + ((ua >> 16) & 1u)) >> 16;
    ub = (ub + 0x7fffu + ((ub >> 16) & 1u)) >> 16;
    return ua | (ub << 16);
}
__device__ inline float blo(uint32_t u) { return __uint_as_float(u << 16); }
__device__ inline float bhi(uint32_t u) { return __uint_as_float(u & 0xffff0000u); }

// ---- K0: W[o][c][k] -> Wcb[m][c] bf16, m = k*64 + o  (A-operand friendly, k-major rows)
__global__ __launch_bounds__(256) void wt_kernel(const float* __restrict__ W,
                                                 uint32_t* __restrict__ Wcb) {
    int i = blockIdx.x * 256 + threadIdx.x;  // i in [0, 4096)
    int m = i >> 5;             // 0..127
    int c = (i & 31) * 2;       // 0..62 even
    int k = m >> 6;             // plane
    int o = m & 63;
    float s0 = W[o * (NC * 2) + c * 2 + k];
    float s1 = W[o * (NC * 2) + (c + 1) * 2 + k];
    Wcb[i] = bf16pack(s0, s1);
}

// ---- K1: MFMA GEMM, both planes at once ----
__global__ __launch_bounds__(256) void ygemm_mfma(const float* __restrict__ x,
                                                  const uint32_t* __restrict__ Wcb,
                                                  const float* __restrict__ bias,
                                                  uint32_t* __restrict__ y0,
                                                  uint32_t* __restrict__ y1) {
    const int b = blockIdx.x & 7;      // XCD pin
    const int tile = blockIdx.x >> 3;
    const int wave = threadIdx.x >> 6;
    const int lane = threadIdx.x & 63;
    const int l15 = lane & 15;
    const int lq = lane >> 4;          // quad 0..3
    const int v = tile * 64 + wave * 16 + l15;
    const int vc = v < NV ? v : NV - 1;
    const float* xb = x + (size_t)b * NC * NV;

    // B fragments: B[k][n], n = lane&15, k = lq*8 + j   (j = frag element)
    union BU { uint32_t u[4]; bf16x8 v; } bu[2];
#pragma unroll
    for (int kt = 0; kt < 2; ++kt) {
        const float* xc = xb + (size_t)(kt * 32 + lq * 8) * NV + vc;
#pragma unroll
        for (int jp = 0; jp < 4; ++jp) {
            float s0 = __builtin_nontemporal_load(xc + (size_t)(2 * jp) * NV);
            float s1 = __builtin_nontemporal_load(xc + (size_t)(2 * jp + 1) * NV);
            bu[kt].u[jp] = bf16pack(s0, s1);
        }
    }

    f32x4 acc[8];
#pragma unroll
    for (int mt = 0; mt < 8; ++mt) acc[mt] = (f32x4){0.f, 0.f, 0.f, 0.f};

    // A fragments: A[m][k], m = mt*16 + (lane&15), k = lq*8 + j -> one dwordx4 each
#pragma unroll
    for (int mt = 0; mt < 8; ++mt) {
#pragma unroll
        for (int kt = 0; kt < 2; ++kt) {
            union { u32x4 q; bf16x8 v; } au;
            au.q = *(const u32x4*)(Wcb + (size_t)(mt * 16 + l15) * 32 + kt * 16 + lq * 4);
            acc[mt] = __builtin_amdgcn_mfma_f32_16x16x32_bf16(au.v, bu[kt].v, acc[mt], 0, 0, 0);
        }
    }

    // D: lane holds D[m = mt*16 + lq*4 + r][n = v], r = 0..3 (consecutive o!)
    if (v < NV) {
        uint32_t* yr0 = y0 + ((size_t)b * NV + v) * 32;
        uint32_t* yr1 = y1 + ((size_t)b * NV + v) * 32;
#pragma unroll
        for (int mt = 0; mt < 8; ++mt) {
            const int mo = mt * 16 + lq * 4;
            f32x4 a = acc[mt];
            if (mt < 4) {  // plane 0: + bias, nt store (read exactly once later)
                const float* bp = bias + mo;
                a[0] += bp[0]; a[1] += bp[1]; a[2] += bp[2]; a[3] += bp[3];
                u32x2 p = {bf16pack(a[0], a[1]), bf16pack(a[2], a[3])};
                __builtin_nontemporal_store(p, (u32x2*)(yr0 + (mo >> 1)));
            } else {       // plane 1: hot gather target, keep cached in L2
                u32x2 p = {bf16pack(a[0], a[1]), bf16pack(a[2], a[3])};
                *(u32x2*)(yr1 + ((mo - 64) >> 1)) = p;
            }
        }
    }
}

// ---- K2: pure gather + combine + store, two 32-o halves to keep VGPRs low ----
__global__ __launch_bounds__(256) void gather_out(const int* __restrict__ nbr,
                                                  const int* __restrict__ deg,
                                                  const uint32_t* __restrict__ y0,
                                                  const uint32_t* __restrict__ y1,
                                                  float* __restrict__ out) {
    const int b = blockIdx.x & 7;  // same XCD pin as producer
    const int tile = blockIdx.x >> 3;
    const int v = tile * 256 + threadIdx.x;
    const int vc = v < NV ? v : NV - 1;
    const bool valid = (v < NV);
    const size_t bv = (size_t)b * NV + vc;

    int idxr[ND];
    {
        const int4* p = reinterpret_cast<const int4*>(nbr + bv * ND);
        int4 a0 = p[0], a1 = p[1], a2 = p[2];
        idxr[0] = a0.x; idxr[1] = a0.y; idxr[2]  = a0.z; idxr[3]  = a0.w;
        idxr[4] = a1.x; idxr[5] = a1.y; idxr[6]  = a1.z; idxr[7]  = a1.w;
        idxr[8] = a2.x; idxr[9] = a2.y; idxr[10] = a2.z; idxr[11] = a2.w;
    }
    const int dg = deg[bv];
    const float inv = 1.0f / (float)dg;
    const uint32_t* y1b = y1 + (size_t)b * NV * 32;

#pragma unroll 1
    for (int h = 0; h < 2; ++h) {   // o-halves [0,32) and [32,64)
        float ns[32];
#pragma unroll
        for (int j = 0; j < 32; ++j) ns[j] = 0.0f;

#pragma unroll
        for (int d = 0; d < ND; ++d) {
            if (d < dg) {
                const u32x4* row =
                    reinterpret_cast<const u32x4*>(y1b + (size_t)idxr[d] * 32 + h * 16);
#pragma unroll
                for (int q = 0; q < 4; ++q) {
                    u32x4 u = row[q];
                    ns[q * 8 + 0] += blo(u[0]); ns[q * 8 + 1] += bhi(u[0]);
                    ns[q * 8 + 2] += blo(u[1]); ns[q * 8 + 3] += bhi(u[1]);
                    ns[q * 8 + 4] += blo(u[2]); ns[q * 8 + 5] += bhi(u[2]);
                    ns[q * 8 + 6] += blo(u[3]); ns[q * 8 + 7] += bhi(u[3]);
                }
            }
        }

        if (valid) {
            const u32x4* srow = reinterpret_cast<const u32x4*>(y0 + bv * 32 + h * 16);
#pragma unroll
            for (int q = 0; q < 4; ++q) {
                u32x4 u = __builtin_nontemporal_load(srow + q);
                float r[8];
                r[0] = blo(u[0]); r[1] = bhi(u[0]); r[2] = blo(u[1]); r[3] = bhi(u[1]);
                r[4] = blo(u[2]); r[5] = bhi(u[2]); r[6] = blo(u[3]); r[7] = bhi(u[3]);
#pragma unroll
                for (int t = 0; t < 8; ++t) {
                    float val = __builtin_fmaf(inv, ns[q * 8 + t], r[t]);
                    __builtin_nontemporal_store(
                        val, out + ((size_t)b * NO + h * 32 + q * 8 + t) * NV + v);
                }
            }
        }
    }
}

// ---- Fallback (workspace too small): correct but slow ----
__global__ __launch_bounds__(64) void fallback_kernel(const float* __restrict__ x,
                                                      const int* __restrict__ nbr,
                                                      const int* __restrict__ deg,
                                                      const float* __restrict__ W,
                                                      const float* __restrict__ bias,
                                                      float* __restrict__ out) {
    const int bvi = blockIdx.x;
    const int b = bvi / NV, v = bvi % NV;
    const int o = threadIdx.x;
    const int degv = deg[bvi];
    const float inv = 1.0f / (float)degv;
    float acc = bias[o];
    for (int c = 0; c < NC; ++c) {
        const float* xc = x + ((size_t)b * NC + c) * NV;
        float m = 0.0f;
        for (int d = 0; d < degv; ++d) m += xc[nbr[(size_t)bvi * ND + d]];
        acc += W[o * (NC * 2) + c * 2] * xc[v] + W[o * (NC * 2) + c * 2 + 1] * (m * inv);
    }
    out[((size_t)b * NO + o) * NV + v] = acc;
}

extern "C" void kernel_launch(void* const* d_in, const int* in_sizes, int n_in,
                              void* d_out, int out_size, void* d_ws, size_t ws_size,
                              hipStream_t stream) {
    const float* x    = (const float*)d_in[0];
    const int*   nbr  = (const int*)d_in[1];
    const int*   deg  = (const int*)d_in[2];
    const float* W    = (const float*)d_in[3];
    const float* bias = (const float*)d_in[4];
    float* out = (float*)d_out;

    const size_t wcb_dw = 4096;                   // 128x64 bf16 as dwords
    const size_t yplane = (size_t)NB * NV * 32;   // dwords per plane
    const size_t need = (wcb_dw + 2 * yplane) * 4;
    if (ws_size >= need) {
        uint32_t* Wcb = (uint32_t*)d_ws;
        uint32_t* y0 = Wcb + wcb_dw;
        uint32_t* y1 = y0 + yplane;
        wt_kernel<<<dim3(16), 256, 0, stream>>>(W, Wcb);
        ygemm_mfma<<<dim3(NB * GT), 256, 0, stream>>>(x, Wcb, bias, y0, y1);
        gather_out<<<dim3(NB * VT), 256, 0, stream>>>(nbr, deg, y0, y1, out);
    } else {
        fallback_kernel<<<dim3(NB * NV), 64, 0, stream>>>(x, nbr, deg, W, bias, out);
    }
}